// Round 12
// baseline (223.921 us; speedup 1.0000x reference)
//
#include <hip/hip_runtime.h>

#define DIM 128        // DIN == DOUT
#define D10 12         // DIM/10
#define ABLK 256       // agg blocks in fat kernel (dispatched FIRST)

typedef __attribute__((ext_vector_type(8))) short bf16x8;
typedef __attribute__((ext_vector_type(4))) float f32x4;

__device__ __forceinline__ void fma4(float4& a, float s, const float4& w) {
    a.x = fmaf(s, w.x, a.x);
    a.y = fmaf(s, w.y, a.y);
    a.z = fmaf(s, w.z, a.z);
    a.w = fmaf(s, w.w, a.w);
}

__device__ __forceinline__ unsigned short f2bf(float f) {
    union { float f; unsigned int u; } v; v.f = f;
    unsigned int u = v.u;
    unsigned int r = (u + 0x7FFFu + ((u >> 16) & 1u)) >> 16;   // RTNE
    return (unsigned short)r;
}

__device__ __forceinline__ float bf2f(unsigned int hi16) {
    union { unsigned int u; float f; } v; v.u = hi16 << 16;
    return v.f;
}

// packed 2x bf16 atomic add (memory-side, fire-and-forget)
__device__ __forceinline__ void atomPkAddBf16(unsigned int* p, unsigned int v) {
    unsigned long long a = (unsigned long long)p;
    asm volatile("global_atomic_pk_add_bf16 %0, %1, off" :: "v"(a), "v"(v) : "memory");
}

__device__ __forceinline__ void atomAddF32(float* p, float v) {
    unsafeAtomicAdd(p, v);
}

// ---------------- s12b = packed bf16x2 of (x@W)[:, :12]  (fp32 math) ----------------
// 64 rows/block; also fuses the W->Wt bf16 transpose (first 64 blocks).

__global__ __launch_bounds__(256) void k_s12(const float4* __restrict__ xv,
                                             const float* __restrict__ W,
                                             const float4* __restrict__ Wv,
                                             unsigned short* __restrict__ Wt,
                                             unsigned int* __restrict__ s12b, int n) {
    __shared__ float4 xsf[64 * 33];
    __shared__ float4 w12[128 * 3];

    int tid = threadIdx.x;
    int rowbase = blockIdx.x * 64;

    // fused Wt transpose: Wt[nn][k] = bf16(W[k][nn])
    int gwt = blockIdx.x * 256 + tid;
    if (gwt < DIM * DIM) {
        int k = gwt >> 7, nn = gwt & 127;
        Wt[nn * DIM + k] = f2bf(W[gwt]);
    }

    for (int i = tid; i < 128 * 3; i += 256) {
        int k = i / 3, q = i - k * 3;
        w12[i] = Wv[k * 32 + q];
    }
    for (int i = tid; i < 64 * 32; i += 256) {
        int r = rowbase + (i >> 5);
        float4 v; v.x = v.y = v.z = v.w = 0.f;
        if (r < n) v = xv[(size_t)r * 32 + (i & 31)];
        xsf[(i >> 5) * 33 + (i & 31)] = v;
    }
    __syncthreads();

    if (tid < 192) {
        int lrow = tid / 3;
        int q = tid - lrow * 3;
        const float4* xr = &xsf[lrow * 33];
        float4 acc; acc.x = acc.y = acc.z = acc.w = 0.f;
#pragma unroll 4
        for (int k4 = 0; k4 < 32; ++k4) {
            float4 v = xr[k4];
            float4 w0 = w12[(k4 * 4 + 0) * 3 + q];
            float4 w1 = w12[(k4 * 4 + 1) * 3 + q];
            float4 w2 = w12[(k4 * 4 + 2) * 3 + q];
            float4 w3 = w12[(k4 * 4 + 3) * 3 + q];
            fma4(acc, v.x, w0); fma4(acc, v.y, w1);
            fma4(acc, v.z, w2); fma4(acc, v.w, w3);
        }
        int grow = rowbase + lrow;
        if (grow < n) {
            unsigned int p0 = (unsigned int)f2bf(acc.x) | ((unsigned int)f2bf(acc.y) << 16);
            unsigned int p1 = (unsigned int)f2bf(acc.z) | ((unsigned int)f2bf(acc.w) << 16);
            s12b[(size_t)grow * 6 + 2 * q]     = p0;
            s12b[(size_t)grow * 6 + 2 * q + 1] = p1;
        }
    }
}

// ---------------- agg init: destination e owned by thread e ----------------
// If row[e]==e, fold edge e in via coalesced write; else zero. Replaces memset
// and removes those edges from the atomic pass.

__global__ void k_init(const unsigned int* __restrict__ s12b,
                       const int* __restrict__ row, const int* __restrict__ col,
                       unsigned int* __restrict__ agg, int n) {
    int e = blockIdx.x * 256 + threadIdx.x;
    if (e >= n) return;
    uint4 a0 = make_uint4(0u, 0u, 0u, 0u);
    uint4 a1 = make_uint4(0u, 0u, 0u, 0u);
    if (row[e] == e) {
        int c = col[e];
        const unsigned int* s = s12b + (size_t)c * 6;
        a0.x = s[0]; a0.y = s[1]; a0.z = s[2]; a0.w = s[3];
        a1.x = s[4]; a1.y = s[5];
        a1.z = 0x00003F80u;                    // deg = bf16(1.0)
    }
    uint4* dst = reinterpret_cast<uint4*>(agg + (size_t)e * 8);
    dst[0] = a0;
    dst[1] = a1;
}

// ---------------- FAT kernel: agg blocks FIRST, then gemm blocks ----------------
// agg (blockIdx < ABLK): grid-stride edges, one 32B pk-atomic sector per edge,
//   skipping edges folded by k_init. Fabric-bound, ~1 block/CU, low CU usage.
// gemm (blockIdx >= ABLK): out[:,12:] = prelu((x@W)[:,12:]+bias). 48KB LDS
//   (x 16KB + Wt 32KB, XOR-swizzled), 3 blocks/CU — backfills remaining slots
//   and executes concurrently under the agg blocks' fabric time.

__global__ __launch_bounds__(256) void k_fat(
    const float4* __restrict__ xv, float* __restrict__ out,
    const uint4* __restrict__ Wtv,
    const float* __restrict__ bias, const float* __restrict__ alpha,
    const unsigned int* __restrict__ s12b,
    const int* __restrict__ row, const int* __restrict__ col,
    unsigned int* __restrict__ agg,
    long long aggTotal, int n)
{
    __shared__ alignas(16) char lds[48 * 1024];

    if ((int)blockIdx.x < ABLK) {
        // ---------- edge aggregation ----------
        long long i = (long long)blockIdx.x * 256 + threadIdx.x;
        long long stride = (long long)ABLK * 256;
        for (long long g = i; g < aggTotal; g += stride) {
            int e = (int)(g >> 3), l = (int)(g & 7);
            if (l < 7) {
                int r = row[e];
                if (e < n && r == e) continue;      // folded by k_init
                unsigned int v = (l < 6) ? s12b[(size_t)col[e] * 6 + l]
                                         : 0x00003F80u;   // bf16(1.0) -> deg
                atomPkAddBf16(&agg[(size_t)r * 8 + l], v);
            }
        }
        return;
    }

    // ---------- gemm ----------
    char* xs  = lds;            // 16 KB
    char* wsm = lds + 16384;    // 32 KB

    int tid = threadIdx.x;
    int rowbase = ((int)blockIdx.x - ABLK) * 64;

#pragma unroll
    for (int ii = 0; ii < 8; ++ii) {
        int i = tid + ii * 256;                  // 2048 x 16B
        int nn = i >> 4, kq = i & 15;
        uint4 v = Wtv[nn * 16 + kq];
        int byte = (nn * 256 + kq * 16) ^ ((nn & 7) << 4);
        *reinterpret_cast<uint4*>(wsm + byte) = v;
    }
#pragma unroll
    for (int ii = 0; ii < 8; ++ii) {
        int i = tid + ii * 256;                  // 2048 x float4
        int lr = i >> 5, c4 = i & 31;
        int r = rowbase + lr;
        float4 v; v.x = v.y = v.z = v.w = 0.f;
        if (r < n) v = xv[(size_t)r * 32 + c4];
        uint2 p;
        p.x = (unsigned int)f2bf(v.x) | ((unsigned int)f2bf(v.y) << 16);
        p.y = (unsigned int)f2bf(v.z) | ((unsigned int)f2bf(v.w) << 16);
        int byte = (lr * 256 + c4 * 8) ^ ((lr & 7) << 4);
        *reinterpret_cast<uint2*>(xs + byte) = p;
    }
    __syncthreads();

    int wv = tid >> 6;
    int lane = tid & 63;
    int lr0 = wv * 16;
    int arow = lr0 + (lane & 15);
    int kgrp = (lane >> 4) * 8;

    f32x4 acc[8];
#pragma unroll
    for (int t = 0; t < 8; ++t) acc[t] = (f32x4){0.f, 0.f, 0.f, 0.f};

#pragma unroll
    for (int kb = 0; kb < 4; ++kb) {
        int koff = kb * 32 + kgrp;
        int abyte = (arow * 256 + koff * 2) ^ ((arow & 7) << 4);
        bf16x8 a = *reinterpret_cast<const bf16x8*>(xs + abyte);
#pragma unroll
        for (int t = 0; t < 8; ++t) {
            int c = t * 16 + (lane & 15);
            int bbyte = (c * 256 + koff * 2) ^ ((c & 7) << 4);
            bf16x8 b = *reinterpret_cast<const bf16x8*>(wsm + bbyte);
            acc[t] = __builtin_amdgcn_mfma_f32_16x16x32_bf16(a, b, acc[t], 0, 0, 0);
        }
    }

    // C/D layout: col=lane&15, row=(lane>>4)*4+reg
    int colbase = lane & 15;
    int rgrp = (lane >> 4) * 4;
    float bi[8], al[8];
#pragma unroll
    for (int t = 0; t < 8; ++t) {
        int c = t * 16 + colbase;
        bi[t] = bias[c];
        al[t] = alpha[c];
    }
#pragma unroll
    for (int j = 0; j < 4; ++j) {
        int r = rowbase + lr0 + rgrp + j;
        if (r >= n) continue;
#pragma unroll
        for (int t = 0; t < 8; ++t) {
            int c = t * 16 + colbase;
            if (t == 0 && colbase < D10) continue;   // cols 0..11 by agg+epi
            float h = acc[t][j];
            h += bi[t];
            h = h >= 0.f ? h : al[t] * h;
            out[(size_t)r * DIM + c] = h;
        }
    }
}

// ---------------- epilogue for cols 0..11: out = prelu(agg/deg + bias) ----------------

__global__ void k_epi12(const uint4* __restrict__ aggv, const float* __restrict__ bias,
                        const float* __restrict__ alpha, float* __restrict__ out, int n) {
    int r = blockIdx.x * blockDim.x + threadIdx.x;
    if (r >= n) return;
    uint4 a0 = aggv[(size_t)r * 2];        // slots 0..3
    uint4 a1 = aggv[(size_t)r * 2 + 1];    // slots 4..7
    float dg = bf2f(a1.z & 0xFFFFu);       // slot 6 low = degree
    float invd = 1.f / (dg >= 1.f ? dg : 1.f);
    unsigned int s[6] = {a0.x, a0.y, a0.z, a0.w, a1.x, a1.y};
    float h[12];
#pragma unroll
    for (int q = 0; q < 6; ++q) {
        h[2 * q]     = bf2f(s[q] & 0xFFFFu) * invd + bias[2 * q];
        h[2 * q + 1] = bf2f(s[q] >> 16)     * invd + bias[2 * q + 1];
    }
#pragma unroll
    for (int c = 0; c < 12; ++c) {
        float v = h[c];
        h[c] = v >= 0.f ? v : alpha[c] * v;
    }
    float4* o = reinterpret_cast<float4*>(out + (size_t)r * DIM);
    o[0] = make_float4(h[0], h[1], h[2], h[3]);
    o[1] = make_float4(h[4], h[5], h[6], h[7]);
    o[2] = make_float4(h[8], h[9], h[10], h[11]);
}

// ---------------- tier E legacy (tiny workspace fallback) ----------------

__global__ void k_count_deg(const int* __restrict__ row, int E, int* __restrict__ deg) {
    int i = blockIdx.x * blockDim.x + threadIdx.x;
    int stride = gridDim.x * blockDim.x;
    for (; i < E; i += stride) atomicAdd(&deg[row[i]], 1);
}

__global__ void k_edge_atomic(const float4* __restrict__ xv, const int* __restrict__ row,
                              const int* __restrict__ col, int E, float* __restrict__ out) {
    int i = blockIdx.x * blockDim.x + threadIdx.x;
    int stride = gridDim.x * blockDim.x;
    int total = E * 32;
    for (; i < total; i += stride) {
        int e = i >> 5, lane = i & 31;
        int r = row[e], c = col[e];
        float4 v = xv[(size_t)c * 32 + lane];
        float* dst = out + (size_t)r * DIM + lane * 4;
        atomAddF32(dst + 0, v.x);
        atomAddF32(dst + 1, v.y);
        atomAddF32(dst + 2, v.z);
        atomAddF32(dst + 3, v.w);
    }
}

__global__ __launch_bounds__(256) void k_final_legacy(const float4* __restrict__ xv,
                                                      float4* __restrict__ outv,
                                                      const float4* __restrict__ Wv,
                                                      const float4* __restrict__ biasv,
                                                      const float4* __restrict__ alphav,
                                                      const int* __restrict__ deg, int n) {
    __shared__ float4 Ws4[DIM * 32];
    __shared__ float4 vs4[2][32 * 32];

    int tid = threadIdx.x;
    int rowbase = blockIdx.x * 32;
    if (rowbase >= n) return;

    for (int i = tid; i < DIM * 32; i += 256) Ws4[i] = Wv[i];
    for (int i = tid; i < 32 * 32; i += 256) {
        int r = rowbase + (i >> 5);
        if (r < n) {
            vs4[0][i] = outv[(size_t)r * 32 + (i & 31)];
            vs4[1][i] = xv[(size_t)r * 32 + (i & 31)];
        }
    }
    __syncthreads();

    int tx = tid & 31;
    int ty = tid >> 5;
    int r0 = ty * 4;
    const float4* V = (tx < (D10 / 4)) ? vs4[0] : vs4[1];

    float4 acc[4];
#pragma unroll
    for (int r = 0; r < 4; r++) { acc[r].x = acc[r].y = acc[r].z = acc[r].w = 0.f; }

#pragma unroll 8
    for (int k4 = 0; k4 < 32; k4++) {
        float4 w0 = Ws4[(k4 * 4 + 0) * 32 + tx];
        float4 w1 = Ws4[(k4 * 4 + 1) * 32 + tx];
        float4 w2 = Ws4[(k4 * 4 + 2) * 32 + tx];
        float4 w3 = Ws4[(k4 * 4 + 3) * 32 + tx];
#pragma unroll
        for (int r = 0; r < 4; r++) {
            float4 v = V[(r0 + r) * 32 + k4];
            fma4(acc[r], v.x, w0); fma4(acc[r], v.y, w1);
            fma4(acc[r], v.z, w2); fma4(acc[r], v.w, w3);
        }
    }

    float4 b4 = biasv[tx];
    float4 a4 = alphav[tx];
#pragma unroll
    for (int r = 0; r < 4; r++) {
        int row = rowbase + r0 + r;
        if (row >= n) continue;
        float4 h = acc[r];
        if (tx < (D10 / 4)) {
            int d = deg[row];
            float invd = 1.0f / (float)(d > 0 ? d : 1);
            h.x *= invd; h.y *= invd; h.z *= invd; h.w *= invd;
        }
        h.x += b4.x; h.y += b4.y; h.z += b4.z; h.w += b4.w;
        h.x = h.x >= 0.f ? h.x : a4.x * h.x;
        h.y = h.y >= 0.f ? h.y : a4.y * h.y;
        h.z = h.z >= 0.f ? h.z : a4.z * h.z;
        h.w = h.w >= 0.f ? h.w : a4.w * h.w;
        outv[(size_t)row * 32 + tx] = h;
    }
}

// ---------------- launcher ----------------

extern "C" void kernel_launch(void* const* d_in, const int* in_sizes, int n_in,
                              void* d_out, int out_size, void* d_ws, size_t ws_size,
                              hipStream_t stream) {
    const float* x     = (const float*)d_in[0];
    const float* W     = (const float*)d_in[1];
    const float* bias  = (const float*)d_in[2];
    const float* alpha = (const float*)d_in[3];
    const int*   ei    = (const int*)d_in[4];

    int N = in_sizes[0] / DIM;
    int E = in_sizes[4] / 2;
    const int* row = ei;
    const int* col = ei + E;
    float* out = (float*)d_out;

    int gemmBlocks = (N + 63) / 64;
    size_t wt_bytes = (size_t)DIM * DIM * 2;   // 32 KB, 32B-aligned

    // Tier A: Wt | s12b[6N] u32 | agg[8N] u32 (32B-aligned rows)
    size_t need_A = wt_bytes + (size_t)(6 + 8) * N * 4;
    size_t need_E = (size_t)N * 4;

    if (ws_size >= need_A) {
        unsigned short* Wt   = (unsigned short*)d_ws;
        unsigned int* s12b   = (unsigned int*)((char*)d_ws + wt_bytes);
        unsigned int* agg    = s12b + (size_t)6 * N;   // 6N*4 % 32 == 0 -> aligned

        k_s12<<<gemmBlocks, 256, 0, stream>>>((const float4*)x, W, (const float4*)W,
                                              Wt, s12b, N);
        k_init<<<(N + 255) / 256, 256, 0, stream>>>(s12b, row, col, agg, N);
        long long aggTotal = (long long)E * 8;
        k_fat<<<ABLK + gemmBlocks, 256, 0, stream>>>(
            (const float4*)x, out, (const uint4*)Wt, bias, alpha,
            s12b, row, col, agg, aggTotal, N);
        k_epi12<<<(N + 255) / 256, 256, 0, stream>>>((const uint4*)agg, bias, alpha, out, N);
    } else if (ws_size >= need_E) {
        int* deg = (int*)d_ws;
        hipMemsetAsync(out, 0, (size_t)N * DIM * sizeof(float), stream);
        hipMemsetAsync(deg, 0, (size_t)N * sizeof(int), stream);
        k_count_deg<<<2048, 256, 0, stream>>>(row, E, deg);
        k_edge_atomic<<<4096, 256, 0, stream>>>((const float4*)x, row, col, E, out);
        k_final_legacy<<<(N + 31) / 32, 256, 0, stream>>>((const float4*)x, (float4*)out,
                                                          (const float4*)W, (const float4*)bias,
                                                          (const float4*)alpha, deg, N);
    }
}

// Round 13
// 119.006 us; speedup vs baseline: 1.8816x; 1.8816x over previous
//
#include <hip/hip_runtime.h>

#define DIM 128        // DIN == DOUT
#define D10 12         // DIM/10

typedef __attribute__((ext_vector_type(8))) short bf16x8;
typedef __attribute__((ext_vector_type(4))) float f32x4;

__device__ __forceinline__ void fma4(float4& a, float s, const float4& w) {
    a.x = fmaf(s, w.x, a.x);
    a.y = fmaf(s, w.y, a.y);
    a.z = fmaf(s, w.z, a.z);
    a.w = fmaf(s, w.w, a.w);
}

__device__ __forceinline__ unsigned short f2bf(float f) {
    union { float f; unsigned int u; } v; v.f = f;
    unsigned int u = v.u;
    unsigned int r = (u + 0x7FFFu + ((u >> 16) & 1u)) >> 16;   // RTNE
    return (unsigned short)r;
}

__device__ __forceinline__ float bf2f(unsigned int hi16) {
    union { unsigned int u; float f; } v; v.u = hi16 << 16;
    return v.f;
}

// packed 2x bf16 atomic add (memory-side, fire-and-forget)
__device__ __forceinline__ void atomPkAddBf16(unsigned int* p, unsigned int v) {
    unsigned long long a = (unsigned long long)p;
    asm volatile("global_atomic_pk_add_bf16 %0, %1, off" :: "v"(a), "v"(v) : "memory");
}

__device__ __forceinline__ void atomAddF32(float* p, float v) {
    unsafeAtomicAdd(p, v);
}

// ---------------- W transpose + bf16 cast: Wt[n][k] = bf16(W[k][n]) ----------------

__global__ void k_wt(const float* __restrict__ W, unsigned short* __restrict__ Wt) {
    int i = blockIdx.x * 256 + threadIdx.x;
    if (i >= DIM * DIM) return;
    int k = i >> 7, nn = i & 127;
    Wt[nn * DIM + k] = f2bf(W[i]);
}

// ---------------- fused MFMA GEMM (r9-proven, 48KB LDS) ----------------
// s12b = packed bf16x2 of (x@W)[:, :12]; out[:, 12:] = prelu((x@W)[:, 12:] + bias)
// 256 thr = 4 waves, 64 rows/block. LDS: x 16KB + Wt 32KB, XOR-swizzled.

__global__ __launch_bounds__(256) void k_gemm(
    const float4* __restrict__ xv, float* __restrict__ out,
    const uint4* __restrict__ Wtv,            // bf16 Wt[n][k]
    const float* __restrict__ bias, const float* __restrict__ alpha,
    unsigned int* __restrict__ s12b, int n)
{
    __shared__ alignas(16) char lds[48 * 1024];
    char* xs  = lds;            // 64 rows x 128 k x 2B = 16 KB
    char* wsm = lds + 16384;    // 128 n  x 128 k x 2B = 32 KB

    int tid = threadIdx.x;
    int rowbase = blockIdx.x * 64;

#pragma unroll
    for (int ii = 0; ii < 8; ++ii) {
        int i = tid + ii * 256;                  // 2048 x 16B
        int nn = i >> 4, kq = i & 15;
        uint4 v = Wtv[nn * 16 + kq];
        int byte = (nn * 256 + kq * 16) ^ ((nn & 7) << 4);
        *reinterpret_cast<uint4*>(wsm + byte) = v;
    }
#pragma unroll
    for (int ii = 0; ii < 8; ++ii) {
        int i = tid + ii * 256;                  // 2048 x float4
        int lr = i >> 5, c4 = i & 31;
        int r = rowbase + lr;
        float4 v; v.x = v.y = v.z = v.w = 0.f;
        if (r < n) v = xv[(size_t)r * 32 + c4];
        uint2 p;
        p.x = (unsigned int)f2bf(v.x) | ((unsigned int)f2bf(v.y) << 16);
        p.y = (unsigned int)f2bf(v.z) | ((unsigned int)f2bf(v.w) << 16);
        int byte = (lr * 256 + c4 * 8) ^ ((lr & 7) << 4);
        *reinterpret_cast<uint2*>(xs + byte) = p;
    }
    __syncthreads();

    int wv = tid >> 6;
    int lane = tid & 63;
    int lr0 = wv * 16;
    int arow = lr0 + (lane & 15);
    int kgrp = (lane >> 4) * 8;

    f32x4 acc[8];
#pragma unroll
    for (int t = 0; t < 8; ++t) acc[t] = (f32x4){0.f, 0.f, 0.f, 0.f};

#pragma unroll
    for (int kb = 0; kb < 4; ++kb) {
        int koff = kb * 32 + kgrp;
        int abyte = (arow * 256 + koff * 2) ^ ((arow & 7) << 4);
        bf16x8 a = *reinterpret_cast<const bf16x8*>(xs + abyte);
#pragma unroll
        for (int t = 0; t < 8; ++t) {
            int c = t * 16 + (lane & 15);
            int bbyte = (c * 256 + koff * 2) ^ ((c & 7) << 4);
            bf16x8 b = *reinterpret_cast<const bf16x8*>(wsm + bbyte);
            acc[t] = __builtin_amdgcn_mfma_f32_16x16x32_bf16(a, b, acc[t], 0, 0, 0);
        }
    }

    // C/D layout: col=lane&15, row=(lane>>4)*4+reg
    int colbase = lane & 15;
    int rgrp = (lane >> 4) * 4;
    float bi[8], al[8];
#pragma unroll
    for (int t = 0; t < 8; ++t) {
        int c = t * 16 + colbase;
        bi[t] = bias[c];
        al[t] = alpha[c];
    }
#pragma unroll
    for (int j = 0; j < 4; ++j) {
        int r = rowbase + lr0 + rgrp + j;
        if (r >= n) continue;
#pragma unroll
        for (int t = 0; t < 8; ++t) {
            int c = t * 16 + colbase;
            float h = acc[t][j];
            if (t == 0 && colbase < D10) {
                // pack pairs (even colbase keeps c,c+1) — partner lane shares r
                float h1 = __shfl_xor(h, 1, 64);
                if ((colbase & 1) == 0) {
                    unsigned int pk = (unsigned int)f2bf(h) |
                                      ((unsigned int)f2bf(h1) << 16);
                    s12b[(size_t)r * 6 + (colbase >> 1)] = pk;
                }
            } else {
                h += bi[t];
                h = h >= 0.f ? h : al[t] * h;
                out[(size_t)r * DIM + c] = h;
            }
        }
    }
}

// ---------------- agg init: destination e owned by thread e ----------------
// If row[e]==e, fold edge e in via coalesced write; else zero. Replaces memset
// and removes those edges from the atomic pass.

__global__ void k_init(const unsigned int* __restrict__ s12b,
                       const int* __restrict__ row, const int* __restrict__ col,
                       unsigned int* __restrict__ agg, int n) {
    int e = blockIdx.x * 256 + threadIdx.x;
    if (e >= n) return;
    uint4 a0 = make_uint4(0u, 0u, 0u, 0u);
    uint4 a1 = make_uint4(0u, 0u, 0u, 0u);
    if (row[e] == e) {
        int c = col[e];
        const unsigned int* s = s12b + (size_t)c * 6;
        a0.x = s[0]; a0.y = s[1]; a0.z = s[2]; a0.w = s[3];
        a1.x = s[4]; a1.y = s[5];
        a1.z = 0x00003F80u;                    // deg = bf16(1.0)
    }
    uint4* dst = reinterpret_cast<uint4*>(agg + (size_t)e * 8);
    dst[0] = a0;
    dst[1] = a1;
}

// ---------------- edge aggregation: ONE 32B sector per edge ----------------
// agg row = 8 u32 (32B aligned): slots 0..5 = pk payload, slot 6 = deg as bf16 1.0.
// Edges with e<n && row[e]==e were folded in by k_init — skipped here.

__global__ void k_edge_agg(const unsigned int* __restrict__ s12b,
                           const int* __restrict__ row, const int* __restrict__ col,
                           long long total, unsigned int* __restrict__ agg, int n) {
    long long i = (long long)blockIdx.x * blockDim.x + threadIdx.x;
    long long stride = (long long)gridDim.x * blockDim.x;
    for (long long g = i; g < total; g += stride) {
        int e = (int)(g >> 3), l = (int)(g & 7);
        if (l < 7) {
            int r = row[e];
            if (e < n && r == e) continue;      // handled by k_init
            unsigned int v = (l < 6) ? s12b[(size_t)col[e] * 6 + l]
                                     : 0x00003F80u;   // bf16(1.0) -> deg
            atomPkAddBf16(&agg[(size_t)r * 8 + l], v);
        }
    }
}

// ---------------- epilogue for cols 0..11: out = prelu(agg/deg + bias) ----------------

__global__ void k_epi12(const uint4* __restrict__ aggv, const float* __restrict__ bias,
                        const float* __restrict__ alpha, float* __restrict__ out, int n) {
    int r = blockIdx.x * blockDim.x + threadIdx.x;
    if (r >= n) return;
    uint4 a0 = aggv[(size_t)r * 2];        // slots 0..3
    uint4 a1 = aggv[(size_t)r * 2 + 1];    // slots 4..7
    float dg = bf2f(a1.z & 0xFFFFu);       // slot 6 low = degree
    float invd = 1.f / (dg >= 1.f ? dg : 1.f);
    unsigned int s[6] = {a0.x, a0.y, a0.z, a0.w, a1.x, a1.y};
    float h[12];
#pragma unroll
    for (int q = 0; q < 6; ++q) {
        h[2 * q]     = bf2f(s[q] & 0xFFFFu) * invd + bias[2 * q];
        h[2 * q + 1] = bf2f(s[q] >> 16)     * invd + bias[2 * q + 1];
    }
#pragma unroll
    for (int c = 0; c < 12; ++c) {
        float v = h[c];
        h[c] = v >= 0.f ? v : alpha[c] * v;
    }
    float4* o = reinterpret_cast<float4*>(out + (size_t)r * DIM);
    o[0] = make_float4(h[0], h[1], h[2], h[3]);
    o[1] = make_float4(h[4], h[5], h[6], h[7]);
    o[2] = make_float4(h[8], h[9], h[10], h[11]);
}

// ---------------- tier E legacy (tiny workspace fallback) ----------------

__global__ void k_count_deg(const int* __restrict__ row, int E, int* __restrict__ deg) {
    int i = blockIdx.x * blockDim.x + threadIdx.x;
    int stride = gridDim.x * blockDim.x;
    for (; i < E; i += stride) atomicAdd(&deg[row[i]], 1);
}

__global__ void k_edge_atomic(const float4* __restrict__ xv, const int* __restrict__ row,
                              const int* __restrict__ col, int E, float* __restrict__ out) {
    int i = blockIdx.x * blockDim.x + threadIdx.x;
    int stride = gridDim.x * blockDim.x;
    int total = E * 32;
    for (; i < total; i += stride) {
        int e = i >> 5, lane = i & 31;
        int r = row[e], c = col[e];
        float4 v = xv[(size_t)c * 32 + lane];
        float* dst = out + (size_t)r * DIM + lane * 4;
        atomAddF32(dst + 0, v.x);
        atomAddF32(dst + 1, v.y);
        atomAddF32(dst + 2, v.z);
        atomAddF32(dst + 3, v.w);
    }
}

__global__ __launch_bounds__(256) void k_final_legacy(const float4* __restrict__ xv,
                                                      float4* __restrict__ outv,
                                                      const float4* __restrict__ Wv,
                                                      const float4* __restrict__ biasv,
                                                      const float4* __restrict__ alphav,
                                                      const int* __restrict__ deg, int n) {
    __shared__ float4 Ws4[DIM * 32];
    __shared__ float4 vs4[2][32 * 32];

    int tid = threadIdx.x;
    int rowbase = blockIdx.x * 32;
    if (rowbase >= n) return;

    for (int i = tid; i < DIM * 32; i += 256) Ws4[i] = Wv[i];
    for (int i = tid; i < 32 * 32; i += 256) {
        int r = rowbase + (i >> 5);
        if (r < n) {
            vs4[0][i] = outv[(size_t)r * 32 + (i & 31)];
            vs4[1][i] = xv[(size_t)r * 32 + (i & 31)];
        }
    }
    __syncthreads();

    int tx = tid & 31;
    int ty = tid >> 5;
    int r0 = ty * 4;
    const float4* V = (tx < (D10 / 4)) ? vs4[0] : vs4[1];

    float4 acc[4];
#pragma unroll
    for (int r = 0; r < 4; r++) { acc[r].x = acc[r].y = acc[r].z = acc[r].w = 0.f; }

#pragma unroll 8
    for (int k4 = 0; k4 < 32; k4++) {
        float4 w0 = Ws4[(k4 * 4 + 0) * 32 + tx];
        float4 w1 = Ws4[(k4 * 4 + 1) * 32 + tx];
        float4 w2 = Ws4[(k4 * 4 + 2) * 32 + tx];
        float4 w3 = Ws4[(k4 * 4 + 3) * 32 + tx];
#pragma unroll
        for (int r = 0; r < 4; r++) {
            float4 v = V[(r0 + r) * 32 + k4];
            fma4(acc[r], v.x, w0); fma4(acc[r], v.y, w1);
            fma4(acc[r], v.z, w2); fma4(acc[r], v.w, w3);
        }
    }

    float4 b4 = biasv[tx];
    float4 a4 = alphav[tx];
#pragma unroll
    for (int r = 0; r < 4; r++) {
        int row = rowbase + r0 + r;
        if (row >= n) continue;
        float4 h = acc[r];
        if (tx < (D10 / 4)) {
            int d = deg[row];
            float invd = 1.0f / (float)(d > 0 ? d : 1);
            h.x *= invd; h.y *= invd; h.z *= invd; h.w *= invd;
        }
        h.x += b4.x; h.y += b4.y; h.z += b4.z; h.w += b4.w;
        h.x = h.x >= 0.f ? h.x : a4.x * h.x;
        h.y = h.y >= 0.f ? h.y : a4.y * h.y;
        h.z = h.z >= 0.f ? h.z : a4.z * h.z;
        h.w = h.w >= 0.f ? h.w : a4.w * h.w;
        outv[(size_t)row * 32 + tx] = h;
    }
}

// ---------------- launcher ----------------

extern "C" void kernel_launch(void* const* d_in, const int* in_sizes, int n_in,
                              void* d_out, int out_size, void* d_ws, size_t ws_size,
                              hipStream_t stream) {
    const float* x     = (const float*)d_in[0];
    const float* W     = (const float*)d_in[1];
    const float* bias  = (const float*)d_in[2];
    const float* alpha = (const float*)d_in[3];
    const int*   ei    = (const int*)d_in[4];

    int N = in_sizes[0] / DIM;
    int E = in_sizes[4] / 2;
    const int* row = ei;
    const int* col = ei + E;
    float* out = (float*)d_out;

    int gemmBlocks = (N + 63) / 64;
    size_t wt_bytes = (size_t)DIM * DIM * 2;   // 32 KB, 32B-aligned

    // Tier A: Wt | s12b[6N] u32 | agg[8N] u32 (32B-aligned rows)
    size_t need_A = wt_bytes + (size_t)(6 + 8) * N * 4;
    size_t need_E = (size_t)N * 4;

    if (ws_size >= need_A) {
        unsigned short* Wt   = (unsigned short*)d_ws;
        unsigned int* s12b   = (unsigned int*)((char*)d_ws + wt_bytes);
        unsigned int* agg    = s12b + (size_t)6 * N;   // 6N*4 % 32 == 0 -> aligned

        k_wt<<<(DIM * DIM + 255) / 256, 256, 0, stream>>>(W, Wt);
        k_gemm<<<gemmBlocks, 256, 0, stream>>>((const float4*)x, out, (const uint4*)Wt,
                                               bias, alpha, s12b, N);
        k_init<<<(N + 255) / 256, 256, 0, stream>>>(s12b, row, col, agg, N);
        long long aggTotal = (long long)E * 8;
        k_edge_agg<<<4096, 256, 0, stream>>>(s12b, row, col, aggTotal, agg, N);
        k_epi12<<<(N + 255) / 256, 256, 0, stream>>>((const uint4*)agg, bias, alpha, out, N);
    } else if (ws_size >= need_E) {
        int* deg = (int*)d_ws;
        hipMemsetAsync(out, 0, (size_t)N * DIM * sizeof(float), stream);
        hipMemsetAsync(deg, 0, (size_t)N * sizeof(int), stream);
        k_count_deg<<<2048, 256, 0, stream>>>(row, E, deg);
        k_edge_atomic<<<4096, 256, 0, stream>>>((const float4*)x, row, col, E, out);
        k_final_legacy<<<(N + 31) / 32, 256, 0, stream>>>((const float4*)x, (float4*)out,
                                                          (const float4*)W, (const float4*)bias,
                                                          (const float4*)alpha, deg, N);
    }
}

// Round 14
// 118.453 us; speedup vs baseline: 1.8904x; 1.0047x over previous
//
#include <hip/hip_runtime.h>

#define DIM 128        // DIN == DOUT
#define D10 12         // DIM/10

typedef __attribute__((ext_vector_type(8))) short bf16x8;
typedef __attribute__((ext_vector_type(4))) float f32x4;

__device__ __forceinline__ void fma4(float4& a, float s, const float4& w) {
    a.x = fmaf(s, w.x, a.x);
    a.y = fmaf(s, w.y, a.y);
    a.z = fmaf(s, w.z, a.z);
    a.w = fmaf(s, w.w, a.w);
}

__device__ __forceinline__ unsigned short f2bf(float f) {
    union { float f; unsigned int u; } v; v.f = f;
    unsigned int u = v.u;
    unsigned int r = (u + 0x7FFFu + ((u >> 16) & 1u)) >> 16;   // RTNE
    return (unsigned short)r;
}

__device__ __forceinline__ float bf2f(unsigned int hi16) {
    union { unsigned int u; float f; } v; v.u = hi16 << 16;
    return v.f;
}

// packed 2x bf16 atomic add (memory-side, fire-and-forget)
__device__ __forceinline__ void atomPkAddBf16(unsigned int* p, unsigned int v) {
    unsigned long long a = (unsigned long long)p;
    asm volatile("global_atomic_pk_add_bf16 %0, %1, off" :: "v"(a), "v"(v) : "memory");
}

__device__ __forceinline__ void atomAddF32(float* p, float v) {
    unsafeAtomicAdd(p, v);
}

#if __has_builtin(__builtin_amdgcn_global_load_lds)
#define HAVE_GLOAD_LDS 1
__device__ __forceinline__ void gload_lds16(const void* g, void* l) {
    __builtin_amdgcn_global_load_lds(
        (const __attribute__((address_space(1))) unsigned int*)g,
        (__attribute__((address_space(3))) unsigned int*)l, 16, 0, 0);
}
#else
#define HAVE_GLOAD_LDS 0
#endif

// ---------------- W transpose + bf16 cast, PRE-SWIZZLED ----------------
// Wt_sw u16 index: (nn*128 + k) ^ ((nn&7)<<3)  ==  byte (nn*256+2k) ^ ((nn&7)<<4)

__global__ void k_wt(const float* __restrict__ W, unsigned short* __restrict__ Wt) {
    int i = blockIdx.x * 256 + threadIdx.x;
    if (i >= DIM * DIM) return;
    int nn = i >> 7, k = i & 127;
    int idx = (nn * 128 + k) ^ ((nn & 7) << 3);
    Wt[idx] = f2bf(W[k * DIM + nn]);
}

// ---------------- fused MFMA GEMM (48KB LDS, gload_lds Wt staging) ----------------
// s12b = packed bf16x2 of (x@W)[:, :12]; out[:, 12:] = prelu((x@W)[:, 12:] + bias)
// 256 thr = 4 waves, 64 rows/block. LDS: x 16KB + Wt 32KB, XOR-swizzled.
// Wt_sw is pre-swizzled in global -> linear async copy lands it swizzled in LDS.

__global__ __launch_bounds__(256) void k_gemm(
    const float4* __restrict__ xv, float* __restrict__ out,
    const unsigned short* __restrict__ Wtsw,   // pre-swizzled bf16 Wt
    const float* __restrict__ bias, const float* __restrict__ alpha,
    unsigned int* __restrict__ s12b, int n)
{
    __shared__ alignas(16) char lds[48 * 1024];
    char* xs  = lds;            // 64 rows x 128 k x 2B = 16 KB
    char* wsm = lds + 16384;    // 128 n  x 128 k x 2B = 32 KB (swizzled content)

    int tid = threadIdx.x;
    int rowbase = blockIdx.x * 64;
    int wv = tid >> 6;
    int lane = tid & 63;

    // ---- stage Wt: async global->LDS, linear copy of pre-swizzled data ----
#if HAVE_GLOAD_LDS
#pragma unroll
    for (int rr = 0; rr < 8; ++rr) {
        int off = (rr * 4 + wv) * 1024 + lane * 16;          // [0, 32K)
        gload_lds16((const char*)Wtsw + off, wsm + off);
    }
#else
#pragma unroll
    for (int ii = 0; ii < 8; ++ii) {
        int i = tid + ii * 256;                               // 2048 x 16B
        int off = i * 16;
        *reinterpret_cast<uint4*>(wsm + off) =
            *reinterpret_cast<const uint4*>((const char*)Wtsw + off);
    }
#endif

    // ---- stage x: reg path (f32->bf16 pack), swizzled LDS writes ----
#pragma unroll
    for (int ii = 0; ii < 8; ++ii) {
        int i = tid + ii * 256;                  // 2048 x float4
        int lr = i >> 5, c4 = i & 31;
        int r = rowbase + lr;
        float4 v; v.x = v.y = v.z = v.w = 0.f;
        if (r < n) v = xv[(size_t)r * 32 + c4];
        uint2 p;
        p.x = (unsigned int)f2bf(v.x) | ((unsigned int)f2bf(v.y) << 16);
        p.y = (unsigned int)f2bf(v.z) | ((unsigned int)f2bf(v.w) << 16);
        int byte = (lr * 256 + c4 * 8) ^ ((lr & 7) << 4);
        *reinterpret_cast<uint2*>(xs + byte) = p;
    }
    __syncthreads();

    int lr0 = wv * 16;
    int arow = lr0 + (lane & 15);
    int kgrp = (lane >> 4) * 8;

    f32x4 acc[8];
#pragma unroll
    for (int t = 0; t < 8; ++t) acc[t] = (f32x4){0.f, 0.f, 0.f, 0.f};

#pragma unroll
    for (int kb = 0; kb < 4; ++kb) {
        int koff = kb * 32 + kgrp;
        int abyte = (arow * 256 + koff * 2) ^ ((arow & 7) << 4);
        bf16x8 a = *reinterpret_cast<const bf16x8*>(xs + abyte);
#pragma unroll
        for (int t = 0; t < 8; ++t) {
            int c = t * 16 + (lane & 15);
            int bbyte = (c * 256 + koff * 2) ^ ((c & 7) << 4);
            bf16x8 b = *reinterpret_cast<const bf16x8*>(wsm + bbyte);
            acc[t] = __builtin_amdgcn_mfma_f32_16x16x32_bf16(a, b, acc[t], 0, 0, 0);
        }
    }

    // C/D layout: col=lane&15, row=(lane>>4)*4+reg
    int colbase = lane & 15;
    int rgrp = (lane >> 4) * 4;
    float bi[8], al[8];
#pragma unroll
    for (int t = 0; t < 8; ++t) {
        int c = t * 16 + colbase;
        bi[t] = bias[c];
        al[t] = alpha[c];
    }
#pragma unroll
    for (int j = 0; j < 4; ++j) {
        int r = rowbase + lr0 + rgrp + j;
        if (r >= n) continue;
#pragma unroll
        for (int t = 0; t < 8; ++t) {
            int c = t * 16 + colbase;
            float h = acc[t][j];
            if (t == 0 && colbase < D10) {
                // pack pairs (even colbase keeps c,c+1) — partner lane shares r
                float h1 = __shfl_xor(h, 1, 64);
                if ((colbase & 1) == 0) {
                    unsigned int pk = (unsigned int)f2bf(h) |
                                      ((unsigned int)f2bf(h1) << 16);
                    s12b[(size_t)r * 6 + (colbase >> 1)] = pk;
                }
            } else {
                h += bi[t];
                h = h >= 0.f ? h : al[t] * h;
                out[(size_t)r * DIM + c] = h;
            }
        }
    }
}

// ---------------- agg init: destination e owned by thread e ----------------

__global__ void k_init(const unsigned int* __restrict__ s12b,
                       const int* __restrict__ row, const int* __restrict__ col,
                       unsigned int* __restrict__ agg, int n) {
    int e = blockIdx.x * 256 + threadIdx.x;
    if (e >= n) return;
    uint4 a0 = make_uint4(0u, 0u, 0u, 0u);
    uint4 a1 = make_uint4(0u, 0u, 0u, 0u);
    if (row[e] == e) {
        int c = col[e];
        const unsigned int* s = s12b + (size_t)c * 6;
        a0.x = s[0]; a0.y = s[1]; a0.z = s[2]; a0.w = s[3];
        a1.x = s[4]; a1.y = s[5];
        a1.z = 0x00003F80u;                    // deg = bf16(1.0)
    }
    uint4* dst = reinterpret_cast<uint4*>(agg + (size_t)e * 8);
    dst[0] = a0;
    dst[1] = a1;
}

// ---------------- edge aggregation: ONE 32B sector per edge ----------------

__global__ void k_edge_agg(const unsigned int* __restrict__ s12b,
                           const int* __restrict__ row, const int* __restrict__ col,
                           long long total, unsigned int* __restrict__ agg, int n) {
    long long i = (long long)blockIdx.x * blockDim.x + threadIdx.x;
    long long stride = (long long)gridDim.x * blockDim.x;
    for (long long g = i; g < total; g += stride) {
        int e = (int)(g >> 3), l = (int)(g & 7);
        if (l < 7) {
            int r = row[e];
            if (e < n && r == e) continue;      // handled by k_init
            unsigned int v = (l < 6) ? s12b[(size_t)col[e] * 6 + l]
                                     : 0x00003F80u;   // bf16(1.0) -> deg
            atomPkAddBf16(&agg[(size_t)r * 8 + l], v);
        }
    }
}

// ---------------- epilogue for cols 0..11 ----------------

__global__ void k_epi12(const uint4* __restrict__ aggv, const float* __restrict__ bias,
                        const float* __restrict__ alpha, float* __restrict__ out, int n) {
    int r = blockIdx.x * blockDim.x + threadIdx.x;
    if (r >= n) return;
    uint4 a0 = aggv[(size_t)r * 2];        // slots 0..3
    uint4 a1 = aggv[(size_t)r * 2 + 1];    // slots 4..7
    float dg = bf2f(a1.z & 0xFFFFu);       // slot 6 low = degree
    float invd = 1.f / (dg >= 1.f ? dg : 1.f);
    unsigned int s[6] = {a0.x, a0.y, a0.z, a0.w, a1.x, a1.y};
    float h[12];
#pragma unroll
    for (int q = 0; q < 6; ++q) {
        h[2 * q]     = bf2f(s[q] & 0xFFFFu) * invd + bias[2 * q];
        h[2 * q + 1] = bf2f(s[q] >> 16)     * invd + bias[2 * q + 1];
    }
#pragma unroll
    for (int c = 0; c < 12; ++c) {
        float v = h[c];
        h[c] = v >= 0.f ? v : alpha[c] * v;
    }
    float4* o = reinterpret_cast<float4*>(out + (size_t)r * DIM);
    o[0] = make_float4(h[0], h[1], h[2], h[3]);
    o[1] = make_float4(h[4], h[5], h[6], h[7]);
    o[2] = make_float4(h[8], h[9], h[10], h[11]);
}

// ---------------- tier E legacy (tiny workspace fallback) ----------------

__global__ void k_count_deg(const int* __restrict__ row, int E, int* __restrict__ deg) {
    int i = blockIdx.x * blockDim.x + threadIdx.x;
    int stride = gridDim.x * blockDim.x;
    for (; i < E; i += stride) atomicAdd(&deg[row[i]], 1);
}

__global__ void k_edge_atomic(const float4* __restrict__ xv, const int* __restrict__ row,
                              const int* __restrict__ col, int E, float* __restrict__ out) {
    int i = blockIdx.x * blockDim.x + threadIdx.x;
    int stride = gridDim.x * blockDim.x;
    int total = E * 32;
    for (; i < total; i += stride) {
        int e = i >> 5, lane = i & 31;
        int r = row[e], c = col[e];
        float4 v = xv[(size_t)c * 32 + lane];
        float* dst = out + (size_t)r * DIM + lane * 4;
        atomAddF32(dst + 0, v.x);
        atomAddF32(dst + 1, v.y);
        atomAddF32(dst + 2, v.z);
        atomAddF32(dst + 3, v.w);
    }
}

__global__ __launch_bounds__(256) void k_final_legacy(const float4* __restrict__ xv,
                                                      float4* __restrict__ outv,
                                                      const float4* __restrict__ Wv,
                                                      const float4* __restrict__ biasv,
                                                      const float4* __restrict__ alphav,
                                                      const int* __restrict__ deg, int n) {
    __shared__ float4 Ws4[DIM * 32];
    __shared__ float4 vs4[2][32 * 32];

    int tid = threadIdx.x;
    int rowbase = blockIdx.x * 32;
    if (rowbase >= n) return;

    for (int i = tid; i < DIM * 32; i += 256) Ws4[i] = Wv[i];
    for (int i = tid; i < 32 * 32; i += 256) {
        int r = rowbase + (i >> 5);
        if (r < n) {
            vs4[0][i] = outv[(size_t)r * 32 + (i & 31)];
            vs4[1][i] = xv[(size_t)r * 32 + (i & 31)];
        }
    }
    __syncthreads();

    int tx = tid & 31;
    int ty = tid >> 5;
    int r0 = ty * 4;
    const float4* V = (tx < (D10 / 4)) ? vs4[0] : vs4[1];

    float4 acc[4];
#pragma unroll
    for (int r = 0; r < 4; r++) { acc[r].x = acc[r].y = acc[r].z = acc[r].w = 0.f; }

#pragma unroll 8
    for (int k4 = 0; k4 < 32; k4++) {
        float4 w0 = Ws4[(k4 * 4 + 0) * 32 + tx];
        float4 w1 = Ws4[(k4 * 4 + 1) * 32 + tx];
        float4 w2 = Ws4[(k4 * 4 + 2) * 32 + tx];
        float4 w3 = Ws4[(k4 * 4 + 3) * 32 + tx];
#pragma unroll
        for (int r = 0; r < 4; r++) {
            float4 v = V[(r0 + r) * 32 + k4];
            fma4(acc[r], v.x, w0); fma4(acc[r], v.y, w1);
            fma4(acc[r], v.z, w2); fma4(acc[r], v.w, w3);
        }
    }

    float4 b4 = biasv[tx];
    float4 a4 = alphav[tx];
#pragma unroll
    for (int r = 0; r < 4; r++) {
        int row = rowbase + r0 + r;
        if (row >= n) continue;
        float4 h = acc[r];
        if (tx < (D10 / 4)) {
            int d = deg[row];
            float invd = 1.0f / (float)(d > 0 ? d : 1);
            h.x *= invd; h.y *= invd; h.z *= invd; h.w *= invd;
        }
        h.x += b4.x; h.y += b4.y; h.z += b4.z; h.w += b4.w;
        h.x = h.x >= 0.f ? h.x : a4.x * h.x;
        h.y = h.y >= 0.f ? h.y : a4.y * h.y;
        h.z = h.z >= 0.f ? h.z : a4.z * h.z;
        h.w = h.w >= 0.f ? h.w : a4.w * h.w;
        outv[(size_t)row * 32 + tx] = h;
    }
}

// ---------------- launcher ----------------

extern "C" void kernel_launch(void* const* d_in, const int* in_sizes, int n_in,
                              void* d_out, int out_size, void* d_ws, size_t ws_size,
                              hipStream_t stream) {
    const float* x     = (const float*)d_in[0];
    const float* W     = (const float*)d_in[1];
    const float* bias  = (const float*)d_in[2];
    const float* alpha = (const float*)d_in[3];
    const int*   ei    = (const int*)d_in[4];

    int N = in_sizes[0] / DIM;
    int E = in_sizes[4] / 2;
    const int* row = ei;
    const int* col = ei + E;
    float* out = (float*)d_out;

    int gemmBlocks = (N + 63) / 64;
    size_t wt_bytes = (size_t)DIM * DIM * 2;   // 32 KB, 32B-aligned

    // Tier A: Wt_sw | s12b[6N] u32 | agg[8N] u32 (32B-aligned rows)
    size_t need_A = wt_bytes + (size_t)(6 + 8) * N * 4;
    size_t need_E = (size_t)N * 4;

    if (ws_size >= need_A) {
        unsigned short* Wt   = (unsigned short*)d_ws;
        unsigned int* s12b   = (unsigned int*)((char*)d_ws + wt_bytes);
        unsigned int* agg    = s12b + (size_t)6 * N;   // 6N*4 % 32 == 0 -> aligned

        k_wt<<<(DIM * DIM + 255) / 256, 256, 0, stream>>>(W, Wt);
        k_gemm<<<gemmBlocks, 256, 0, stream>>>((const float4*)x, out, Wt,
                                               bias, alpha, s12b, N);
        k_init<<<(N + 255) / 256, 256, 0, stream>>>(s12b, row, col, agg, N);
        long long aggTotal = (long long)E * 8;
        k_edge_agg<<<4096, 256, 0, stream>>>(s12b, row, col, aggTotal, agg, N);
        k_epi12<<<(N + 255) / 256, 256, 0, stream>>>((const uint4*)agg, bias, alpha, out, N);
    } else if (ws_size >= need_E) {
        int* deg = (int*)d_ws;
        hipMemsetAsync(out, 0, (size_t)N * DIM * sizeof(float), stream);
        hipMemsetAsync(deg, 0, (size_t)N * sizeof(int), stream);
        k_count_deg<<<2048, 256, 0, stream>>>(row, E, deg);
        k_edge_atomic<<<4096, 256, 0, stream>>>((const float4*)x, row, col, E, out);
        k_final_legacy<<<(N + 31) / 32, 256, 0, stream>>>((const float4*)x, (float4*)out,
                                                          (const float4*)W, (const float4*)bias,
                                                          (const float4*)alpha, deg, N);
    }
}